// Round 9
// baseline (3465.002 us; speedup 1.0000x reference)
//
#include <hip/hip_runtime.h>
#include <hip/hip_bf16.h>

// ---------------------------------------------------------------------------
// RecurrentAutoencoder on MI355X (gfx950).
// e1:   known-good (512 thr, pk_fma, DPP quad ring)          ~950 us
// scan: 2 waves; Up staged into LDS via global_load_lds (dbuf, 32 steps/chunk,
//       counted vmcnt at chunk boundary ONLY). Steady-state step touches LDS
//       only: no global loads, no vmcnt, no 64-bit addr math.
// dec:  standalone known-good fused d1+d2                     ~150 us
// ---------------------------------------------------------------------------

typedef float v2f __attribute__((ext_vector_type(2)));

__device__ __forceinline__ v2f pk_fma(v2f a, v2f b, v2f c) {
  v2f d;
  asm("v_pk_fma_f32 %0, %1, %2, %3" : "=v"(d) : "v"(a), "v"(b), "v"(c));
  return d;
}

__device__ __forceinline__ float sigm(float x) {
  return 1.0f / (1.0f + __expf(-x));
}
__device__ __forceinline__ float tanh_fast(float x) {
  return 1.0f - 2.0f / (__expf(2.0f * x) + 1.0f);
}

// Raw workgroup barrier: waits LDS ops only, does NOT drain vmcnt.
__device__ __forceinline__ void wg_barrier() {
  asm volatile("s_waitcnt lgkmcnt(0)\n\ts_barrier" ::: "memory");
}

template <int CTRL>
__device__ __forceinline__ float dppmv(float v) {
  return __int_as_float(__builtin_amdgcn_update_dpp(
      0, __float_as_int(v), CTRL, 0xF, 0xF, true));
}
#define DPP_XOR1   0xB1
#define DPP_XOR2   0x4E
#define DPP_ROT1   0x93   // quad rotate: dest q <- (q-1)&3
#define DPP_HMIRR  0x141
#define DPP_MIRR   0x140

__device__ __forceinline__ int swzc(int k) { return k + ((k >> 5) << 2); }

#define A_BB 16

// ---------------------------------------------------------------------------
// Stage A (known-good). 512 threads = 8 waves, DPP quad ring, pk_fma.
// ---------------------------------------------------------------------------
__global__ __launch_bounds__(512, 2) void lstm_e1_kernel(
    const float* __restrict__ x,     // [4096][140]
    const float* __restrict__ Wih,   // [512][1]
    const float* __restrict__ Whh,   // [512][128]
    const float* __restrict__ bih,   // [512]
    const float* __restrict__ bhh,   // [512]
    float* __restrict__ h1_out)      // [4096][128]
{
  const int j    = threadIdx.x;
  const int lane = j & 63;
  const int w    = j >> 6;
  const int u    = w * 16 + (lane >> 2);  // 0..127
  const int q    = lane & 3;
  const int b0   = blockIdx.x * A_BB;

  __shared__ float Hs[2][A_BB][144];
  __shared__ float xs[2][A_BB];

  for (int i = j; i < A_BB * 144; i += 512) ((float*)Hs[0])[i] = 0.0f;
  if (j < A_BB) xs[0][j] = x[(b0 + j) * 140];

  v2f wr2[4][16];
#pragma unroll
  for (int g = 0; g < 4; ++g)
#pragma unroll
    for (int k = 0; k < 32; k += 4) {
      const float4 t4 = *(const float4*)&Whh[(g * 128 + u) * 128 + q * 32 + k];
      wr2[g][k / 2 + 0].x = t4.x; wr2[g][k / 2 + 0].y = t4.y;
      wr2[g][k / 2 + 1].x = t4.z; wr2[g][k / 2 + 1].y = t4.w;
    }

  float wih[4], bs[4];
#pragma unroll
  for (int g = 0; g < 4; ++g) {
    wih[g] = Wih[g * 128 + u];
    bs[g]  = bih[g * 128 + u] + bhh[g * 128 + u];
  }

  float c[4]  = {0.f, 0.f, 0.f, 0.f};
  float hr[4] = {0.f, 0.f, 0.f, 0.f};
  __syncthreads();

  int cur = 0;
  for (int t = 0; t < 140; ++t) {
    const int nxt = cur ^ 1;

    v2f R2[4][4];
#pragma unroll
    for (int g = 0; g < 4; ++g)
#pragma unroll
      for (int i = 0; i < 4; ++i) { R2[g][i].x = 0.f; R2[g][i].y = 0.f; }

#pragma unroll
    for (int s = 0; s < 4; ++s) {
      if (s) {
#pragma unroll
        for (int g = 0; g < 4; ++g)
#pragma unroll
          for (int i = 0; i < 4; ++i) {
            R2[g][i].x = dppmv<DPP_ROT1>(R2[g][i].x);
            R2[g][i].y = dppmv<DPP_ROT1>(R2[g][i].y);
          }
      }
      const int cch = (q - 1 - s) & 3;
      const float* hbase = &Hs[cur][cch * 4][q * 36];
#pragma unroll
      for (int i = 0; i < 4; ++i) {
        const float* hrow = hbase + i * 144;
#pragma unroll
        for (int kk = 0; kk < 8; ++kk) {
          const float4 hv = *(const float4*)&hrow[kk * 4];
          v2f h01; h01.x = hv.x; h01.y = hv.y;
          v2f h23; h23.x = hv.z; h23.y = hv.w;
#pragma unroll
          for (int g = 0; g < 4; ++g) {
            R2[g][i] = pk_fma(wr2[g][2 * kk + 0], h01, R2[g][i]);
            R2[g][i] = pk_fma(wr2[g][2 * kk + 1], h23, R2[g][i]);
          }
        }
      }
    }

    if (j < A_BB && (t + 1) < 140) xs[nxt][j] = x[(b0 + j) * 140 + t + 1];

    const float4 xv = *(const float4*)&xs[cur][q * 4];
    const float xa[4] = {xv.x, xv.y, xv.z, xv.w};
#pragma unroll
    for (int i = 0; i < 4; ++i) {
      const float gi = sigm(R2[0][i].x + R2[0][i].y + __builtin_fmaf(wih[0], xa[i], bs[0]));
      const float gf = sigm(R2[1][i].x + R2[1][i].y + __builtin_fmaf(wih[1], xa[i], bs[1]));
      const float gg = tanh_fast(R2[2][i].x + R2[2][i].y + __builtin_fmaf(wih[2], xa[i], bs[2]));
      const float go = sigm(R2[3][i].x + R2[3][i].y + __builtin_fmaf(wih[3], xa[i], bs[3]));
      c[i]  = gf * c[i] + gi * gg;
      hr[i] = go * tanh_fast(c[i]);
      Hs[nxt][q * 4 + i][swzc(u)] = hr[i];
    }
    wg_barrier();
    cur = nxt;
  }

#pragma unroll
  for (int i = 0; i < 4; ++i)
    h1_out[(b0 + q * 4 + i) * 128 + u] = hr[i];
}

// ---------------------------------------------------------------------------
// Stage B input projection, PERMUTED: Up[t][u] = (pre_i,pre_f,pre_g,pre_o).
// ---------------------------------------------------------------------------
__global__ __launch_bounds__(256, 1) void u_pre_kernel(
    const float* __restrict__ h1,   // [4096][128]
    const float* __restrict__ Wih,  // [256][128]
    const float* __restrict__ bih,  // [256]
    const float* __restrict__ bhh,  // [256]
    float* __restrict__ Up)         // [4096][64][4]
{
  const int t = blockIdx.x;
  const int j = threadIdx.x;      // gate row j = g*64 + u
  __shared__ float hs[128];
  if (j < 128) hs[j] = h1[t * 128 + j];
  __syncthreads();
  float acc = bih[j] + bhh[j];
#pragma unroll
  for (int k = 0; k < 128; k += 4) {
    const float4 hv = *(const float4*)&hs[k];
    const float4 wv = *(const float4*)&Wih[j * 128 + k];
    acc += wv.x * hv.x + wv.y * hv.y + wv.z * hv.z + wv.w * hv.w;
  }
  Up[t * 256 + (j & 63) * 4 + (j >> 6)] = acc;
}

// ---------------------------------------------------------------------------
// Stage B serial scan. 128 threads = 2 waves. Thread (u=j>>1, p=j&1): 4 gate
// rows of unit u over k-half [32p,+32) = 128 VGPR weights. Up is staged into
// LDS (double-buffered 32-step chunks) via global_load_lds; the per-step path
// is LDS-only. vmcnt waits only at chunk boundaries (counted, 16).
// ---------------------------------------------------------------------------
__global__ __launch_bounds__(128, 1) void lstm_e2_scan_kernel(
    const float4* __restrict__ Up,  // [4096][64] of (i,f,g,o)
    const float* __restrict__ Whh,  // [256][64]
    float* __restrict__ z_out)      // [64]
{
  const int j    = threadIdx.x;
  const int u    = j >> 1;   // 0..63
  const int p    = j & 1;    // k-half
  const int w    = j >> 6;   // wave 0/1
  const int lane = j & 63;

  __shared__ float4 Uc[2][32][64];   // 64 KB, double-buffered chunks
  __shared__ float hb[2][64];

  // weights: 4 gates x 32 k packed = 128 VGPR
  v2f wr2[4][16];
#pragma unroll
  for (int g = 0; g < 4; ++g)
#pragma unroll
    for (int k = 0; k < 32; k += 4) {
      const float4 t4 = *(const float4*)&Whh[(g * 64 + u) * 64 + p * 32 + k];
      wr2[g][k / 2 + 0].x = t4.x; wr2[g][k / 2 + 0].y = t4.y;
      wr2[g][k / 2 + 1].x = t4.z; wr2[g][k / 2 + 1].y = t4.w;
    }

  if (j < 64) { hb[0][j] = 0.0f; hb[1][j] = 0.0f; }

  // stage chunk CK (32 steps x 64 units x 16B = 32KB) into buffer BUF.
  // wave w covers 1KB blocks {w, w+2, w+4, ...}: 16 issues of 16B/lane.
#define STAGE(BUF, CK)                                                        \
  {                                                                           \
    const char* g_ = (const char*)Up + (CK) * 32768 + w * 1024 + lane * 16;   \
    char* l_ = (char*)&Uc[0][0][0] + (BUF) * 32768 + w * 1024;                \
    _Pragma("unroll")                                                         \
    for (int i_ = 0; i_ < 16; ++i_)                                           \
      __builtin_amdgcn_global_load_lds(                                       \
          (const __attribute__((address_space(1))) unsigned int*)(g_ + i_ * 2048), \
          (__attribute__((address_space(3))) unsigned int*)(l_ + i_ * 2048),  \
          16, 0, 0);                                                          \
  }

  STAGE(0, 0)
  __syncthreads();   // drains vmcnt(0): chunk 0 landed; hb init visible

  float c = 0.0f, h = 0.0f;
  const char* ucol0 = (const char*)&Uc[0][0][u];   // per-lane, loop-invariant
  const char* hrd0  = (const char*)&hb[0][p * 32];
  char*       hwr0  = (char*)&hb[0][u];

  // one LSTM step at LDS byte offset UB+S8*1024; parity = S8&1 (8 | steps/blk)
#define SCAN_STEP(UB, S8)                                                     \
  {                                                                           \
    const float4 Ucur = *(const float4*)((UB) + (S8) * 1024);                 \
    const float* hrow = (const float*)(hrd0 + ((S8) & 1) * 256);              \
    v2f A0, A1, A2, A3;                                                       \
    A0.x = 0.f; A0.y = 0.f; A1 = A0; A2 = A0; A3 = A0;                        \
    _Pragma("unroll")                                                         \
    for (int kk = 0; kk < 8; ++kk) {                                          \
      const float4 hv = *(const float4*)&hrow[kk * 4];                        \
      v2f hx; hx.x = hv.x; hx.y = hv.y;                                       \
      v2f hy; hy.x = hv.z; hy.y = hv.w;                                       \
      A0 = pk_fma(wr2[0][2 * kk], hx, A0); A0 = pk_fma(wr2[0][2 * kk + 1], hy, A0); \
      A1 = pk_fma(wr2[1][2 * kk], hx, A1); A1 = pk_fma(wr2[1][2 * kk + 1], hy, A1); \
      A2 = pk_fma(wr2[2][2 * kk], hx, A2); A2 = pk_fma(wr2[2][2 * kk + 1], hy, A2); \
      A3 = pk_fma(wr2[3][2 * kk], hx, A3); A3 = pk_fma(wr2[3][2 * kk + 1], hy, A3); \
    }                                                                         \
    float a0 = A0.x + A0.y, a1 = A1.x + A1.y;                                 \
    float a2 = A2.x + A2.y, a3 = A3.x + A3.y;                                 \
    a0 += dppmv<DPP_XOR1>(a0); a1 += dppmv<DPP_XOR1>(a1);                     \
    a2 += dppmv<DPP_XOR1>(a2); a3 += dppmv<DPP_XOR1>(a3);                     \
    const float gi = sigm(a0 + Ucur.x);                                       \
    const float gf = sigm(a1 + Ucur.y);                                       \
    const float gg = tanh_fast(a2 + Ucur.z);                                  \
    const float go = sigm(a3 + Ucur.w);                                       \
    c = gf * c + gi * gg;                                                     \
    h = go * tanh_fast(c);                                                    \
    if (p == 0) *(float*)(hwr0 + (((S8) & 1) ^ 1) * 256) = h;                 \
    wg_barrier();                                                             \
  }

  // 32 steps of one chunk: 4 blocks of 8 unrolled steps (immediate offsets)
#define CHUNK(BUF)                                                            \
  {                                                                           \
    const char* ub_ = ucol0 + (BUF) * 32768;                                  \
    _Pragma("unroll 1")                                                       \
    for (int s8o_ = 0; s8o_ < 4; ++s8o_) {                                    \
      _Pragma("unroll")                                                       \
      for (int s8i_ = 0; s8i_ < 8; ++s8i_) { SCAN_STEP(ub_, s8i_) }           \
      ub_ += 8 * 1024;                                                        \
    }                                                                         \
  }

#pragma unroll 1
  for (int ck2 = 0; ck2 < 64; ++ck2) {
    // ---- half A: consume buf 0 (chunk 2*ck2), stage chunk 2*ck2+1 -> buf 1
    STAGE(1, 2 * ck2 + 1)
    asm volatile("s_waitcnt vmcnt(16)" ::: "memory");  // buf0's stage landed
    __builtin_amdgcn_s_barrier();                      // both waves' stages
    CHUNK(0)
    // ---- half B: consume buf 1, stage chunk 2*ck2+2 -> buf 0
    if (ck2 < 63) {
      STAGE(0, 2 * ck2 + 2)
      asm volatile("s_waitcnt vmcnt(16)" ::: "memory");
    } else {
      asm volatile("s_waitcnt vmcnt(0)" ::: "memory");
    }
    __builtin_amdgcn_s_barrier();
    CHUNK(1)
  }
#undef CHUNK
#undef SCAN_STEP
#undef STAGE

  if (p == 0) z_out[u] = h;
}

// ---------------------------------------------------------------------------
// Stage C+D fused decoder (known-good). 512 threads.
// ---------------------------------------------------------------------------
__global__ __launch_bounds__(512, 1) void lstm_dec_kernel(
    const float* __restrict__ z,      // [64]
    const float* __restrict__ Wih1,   // [512][64]
    const float* __restrict__ Whh1,   // [512][128]
    const float* __restrict__ bih1,   // [512]
    const float* __restrict__ bhh1,   // [512]
    const float* __restrict__ Wih2,   // [4][128]
    const float* __restrict__ Whh2,   // [4][1]
    const float* __restrict__ bih2,   // [4]
    const float* __restrict__ bhh2,   // [4]
    float* __restrict__ out)          // [140]
{
  const int j = threadIdx.x;
  const int u = j >> 2;   // 0..127
  const int q = j & 3;

  __shared__ float hd[2][144];
  __shared__ float zs[64];
  __shared__ float act4[4];

  if (j < 64) zs[j] = z[j];
  if (j < 144) hd[0][j] = 0.0f;
  __syncthreads();

  float wr[4][32];
#pragma unroll
  for (int g = 0; g < 4; ++g)
#pragma unroll
    for (int k = 0; k < 32; k += 4)
      *(float4*)&wr[g][k] = *(const float4*)&Whh1[(g * 128 + u) * 128 + q * 32 + k];

  float pre0[4];
#pragma unroll
  for (int g = 0; g < 4; ++g) {
    float acc = bih1[g * 128 + u] + bhh1[g * 128 + u];
#pragma unroll
    for (int k = 0; k < 64; k += 4) {
      const float4 zv = *(const float4*)&zs[k];
      const float4 wv = *(const float4*)&Wih1[(g * 128 + u) * 64 + k];
      acc += wv.x * zv.x + wv.y * zv.y + wv.z * zv.z + wv.w * zv.w;
    }
    pre0[g] = acc;
  }

  const int g2  = j >> 4;
  const int i16 = j & 15;
  float w2d[8] = {0,0,0,0,0,0,0,0};
  if (j < 64) {
#pragma unroll
    for (int e = 0; e < 8; ++e) w2d[e] = Wih2[g2 * 128 + i16 * 8 + e];
  }
  const float bb2_0 = bih2[0] + bhh2[0], wh2_0 = Whh2[0];
  const float bb2_1 = bih2[1] + bhh2[1], wh2_1 = Whh2[1];
  const float bb2_2 = bih2[2] + bhh2[2], wh2_2 = Whh2[2];
  const float bb2_3 = bih2[3] + bhh2[3], wh2_3 = Whh2[3];

  float c1 = 0.0f;
  float c2 = 0.0f, h2 = 0.0f;

  int cur = 0;
  for (int t = 0; t < 140; ++t) {
    float a0 = 0.f, a1 = 0.f, a2 = 0.f, a3 = 0.f;
#pragma unroll
    for (int kk = 0; kk < 8; ++kk) {
      const float4 hv = *(const float4*)&hd[cur][q * 36 + kk * 4];
      a0 = __builtin_fmaf(wr[0][kk*4+0], hv.x, a0); a0 = __builtin_fmaf(wr[0][kk*4+1], hv.y, a0);
      a0 = __builtin_fmaf(wr[0][kk*4+2], hv.z, a0); a0 = __builtin_fmaf(wr[0][kk*4+3], hv.w, a0);
      a1 = __builtin_fmaf(wr[1][kk*4+0], hv.x, a1); a1 = __builtin_fmaf(wr[1][kk*4+1], hv.y, a1);
      a1 = __builtin_fmaf(wr[1][kk*4+2], hv.z, a1); a1 = __builtin_fmaf(wr[1][kk*4+3], hv.w, a1);
      a2 = __builtin_fmaf(wr[2][kk*4+0], hv.x, a2); a2 = __builtin_fmaf(wr[2][kk*4+1], hv.y, a2);
      a2 = __builtin_fmaf(wr[2][kk*4+2], hv.z, a2); a2 = __builtin_fmaf(wr[2][kk*4+3], hv.w, a2);
      a3 = __builtin_fmaf(wr[3][kk*4+0], hv.x, a3); a3 = __builtin_fmaf(wr[3][kk*4+1], hv.y, a3);
      a3 = __builtin_fmaf(wr[3][kk*4+2], hv.z, a3); a3 = __builtin_fmaf(wr[3][kk*4+3], hv.w, a3);
    }
    a0 += dppmv<DPP_XOR1>(a0); a0 += dppmv<DPP_XOR2>(a0);
    a1 += dppmv<DPP_XOR1>(a1); a1 += dppmv<DPP_XOR2>(a1);
    a2 += dppmv<DPP_XOR1>(a2); a2 += dppmv<DPP_XOR2>(a2);
    a3 += dppmv<DPP_XOR1>(a3); a3 += dppmv<DPP_XOR2>(a3);

    const float gi = sigm(a0 + pre0[0]);
    const float gf = sigm(a1 + pre0[1]);
    const float gg = tanh_fast(a2 + pre0[2]);
    const float go = sigm(a3 + pre0[3]);
    c1 = gf * c1 + gi * gg;
    const float h1v = go * tanh_fast(c1);
    if (q == 0) hd[cur ^ 1][swzc(u)] = h1v;
    wg_barrier();
    cur ^= 1;

    if (j < 64) {
      const int kb = i16 * 8;
      const float4 hA = *(const float4*)&hd[cur][swzc(kb)];
      const float4 hB = *(const float4*)&hd[cur][swzc(kb) + 4];
      float pp = hA.x * w2d[0];
      pp = __builtin_fmaf(hA.y, w2d[1], pp);
      pp = __builtin_fmaf(hA.z, w2d[2], pp);
      pp = __builtin_fmaf(hA.w, w2d[3], pp);
      pp = __builtin_fmaf(hB.x, w2d[4], pp);
      pp = __builtin_fmaf(hB.y, w2d[5], pp);
      pp = __builtin_fmaf(hB.z, w2d[6], pp);
      pp = __builtin_fmaf(hB.w, w2d[7], pp);
      pp += dppmv<DPP_XOR1>(pp);
      pp += dppmv<DPP_XOR2>(pp);
      pp += dppmv<DPP_HMIRR>(pp);
      pp += dppmv<DPP_MIRR>(pp);
      if (i16 == 0) act4[g2] = pp;
      const float4 acts = *(const float4*)&act4[0];  // same-wave, lgkm-ordered
      const float gi2 = sigm(acts.x + bb2_0 + wh2_0 * h2);
      const float gf2 = sigm(acts.y + bb2_1 + wh2_1 * h2);
      const float gg2 = tanh_fast(acts.z + bb2_2 + wh2_2 * h2);
      const float go2 = sigm(acts.w + bb2_3 + wh2_3 * h2);
      c2 = gf2 * c2 + gi2 * gg2;
      h2 = go2 * tanh_fast(c2);
      if (j == 0) out[t] = h2;
    }
  }
}

// ---------------------------------------------------------------------------
extern "C" void kernel_launch(void* const* d_in, const int* in_sizes, int n_in,
                              void* d_out, int out_size, void* d_ws, size_t ws_size,
                              hipStream_t stream) {
  const float* x      = (const float*)d_in[0];
  const float* Wih_e1 = (const float*)d_in[1];
  const float* Whh_e1 = (const float*)d_in[2];
  const float* bih_e1 = (const float*)d_in[3];
  const float* bhh_e1 = (const float*)d_in[4];
  const float* Wih_e2 = (const float*)d_in[5];
  const float* Whh_e2 = (const float*)d_in[6];
  const float* bih_e2 = (const float*)d_in[7];
  const float* bhh_e2 = (const float*)d_in[8];
  const float* Wih_d1 = (const float*)d_in[9];
  const float* Whh_d1 = (const float*)d_in[10];
  const float* bih_d1 = (const float*)d_in[11];
  const float* bhh_d1 = (const float*)d_in[12];
  const float* Wih_d2 = (const float*)d_in[13];
  const float* Whh_d2 = (const float*)d_in[14];
  const float* bih_d2 = (const float*)d_in[15];
  const float* bhh_d2 = (const float*)d_in[16];

  float* out = (float*)d_out;  // 140 floats

  float* h1 = (float*)d_ws;              // 4096*128
  float* Up = h1 + 4096 * 128;           // 4096*256 (permuted [t][u][gate])
  float* zb = Up + 4096 * 256;           // 64

  lstm_e1_kernel<<<4096 / A_BB, 512, 0, stream>>>(x, Wih_e1, Whh_e1, bih_e1, bhh_e1, h1);
  u_pre_kernel<<<4096, 256, 0, stream>>>(h1, Wih_e2, bih_e2, bhh_e2, Up);
  lstm_e2_scan_kernel<<<1, 128, 0, stream>>>((const float4*)Up, Whh_e2, zb);
  lstm_dec_kernel<<<1, 512, 0, stream>>>(zb, Wih_d1, Whh_d1, bih_d1, bhh_d1,
                                         Wih_d2, Whh_d2, bih_d2, bhh_d2, out);
}